// Round 1
// baseline (660.160 us; speedup 1.0000x reference)
//
#include <hip/hip_runtime.h>
#include <hip/hip_bf16.h>
#include <math.h>
#include <stdint.h>

#define EPS 1e-5f

typedef int v4i __attribute__((ext_vector_type(4)));

__device__ __forceinline__ void glds16(const void* g, void* l) {
  __builtin_amdgcn_global_load_lds(
      (const __attribute__((address_space(1))) void*)g,
      (__attribute__((address_space(3))) void*)l, 16, 0, 0);
}

__device__ __forceinline__ signed char q8(float f, float xs) {
  float r = rintf(f * xs);
  r = fminf(fmaxf(r, -128.f), 127.f);
  return (signed char)(int)r;
}

__device__ __forceinline__ float bf2f(unsigned short h) {
  return __builtin_bit_cast(float, (unsigned)h << 16);
}

// ---------------- merged weight abs-sum (3 tensors, 1 launch) ----------------
__global__ __launch_bounds__(256) void absum3_kernel(const float* __restrict__ Wg,
                                                     const float* __restrict__ W1,
                                                     const float* __restrict__ W2,
                                                     float* __restrict__ out) {
  int blk = blockIdx.x;
  const float* w; long n4; float* o; long lb; long nb;
  if (blk < 512)      { w = Wg; n4 = 3932160; o = &out[0]; lb = blk;       nb = 512; }
  else if (blk < 768) { w = W1; n4 = 1048576; o = &out[1]; lb = blk - 512; nb = 256; }
  else                { w = W2; n4 = 1048576; o = &out[2]; lb = blk - 768; nb = 256; }
  const float4* w4 = (const float4*)w;
  float s = 0.f;
  for (long i = lb * 256 + threadIdx.x; i < n4; i += nb * 256) {
    float4 v = w4[i];
    s += fabsf(v.x) + fabsf(v.y) + fabsf(v.z) + fabsf(v.w);
  }
  for (int off = 32; off; off >>= 1) s += __shfl_down(s, off);
  __shared__ float sb[4];
  int lane = threadIdx.x & 63, wid = threadIdx.x >> 6;
  if (lane == 0) sb[wid] = s;
  __syncthreads();
  if (threadIdx.x == 0) atomicAdd(o, sb[0] + sb[1] + sb[2] + sb[3]);
}

// ---------------- merged ternarize (3 tensors, 1 launch) ----------------
__global__ __launch_bounds__(256) void ternarize3_kernel(const float* __restrict__ Wg,
                                                         const float* __restrict__ W1,
                                                         const float* __restrict__ W2,
                                                         signed char* __restrict__ tg,
                                                         signed char* __restrict__ t1,
                                                         signed char* __restrict__ t2,
                                                         const float* __restrict__ sums) {
  int blk = blockIdx.x;
  const float* w; signed char* t; long n4; float ws; long lb; long nb;
  if (blk < 1024) {
    w = Wg; t = tg; n4 = 3932160; ws = sums[0] * (1.f / 15728640.f) + EPS; lb = blk; nb = 1024;
  } else if (blk < 1536) {
    w = W1; t = t1; n4 = 1048576; ws = sums[1] * (1.f / 4194304.f) + EPS; lb = blk - 1024; nb = 512;
  } else {
    w = W2; t = t2; n4 = 1048576; ws = sums[2] * (1.f / 4194304.f) + EPS; lb = blk - 1536; nb = 512;
  }
  const float4* w4 = (const float4*)w;
  char4* t4 = (char4*)t;
  for (long i = lb * 256 + threadIdx.x; i < n4; i += nb * 256) {
    float4 v = w4[i];
    char4 c;
    c.x = (signed char)(int)fminf(fmaxf(rintf(v.x / ws), -1.f), 1.f);
    c.y = (signed char)(int)fminf(fmaxf(rintf(v.y / ws), -1.f), 1.f);
    c.z = (signed char)(int)fminf(fmaxf(rintf(v.z / ws), -1.f), 1.f);
    c.w = (signed char)(int)fminf(fmaxf(rintf(v.w / ws), -1.f), 1.f);
    t4[i] = c;
  }
}

// ---------------- LN1: write xn fp32 + per-row absmax ----------------
__global__ __launch_bounds__(256) void ln_rowmax_kernel(const float* __restrict__ x,
                                                        const float* __restrict__ w,
                                                        const float* __restrict__ b,
                                                        float* __restrict__ xn,
                                                        float* __restrict__ rowmax) {
  int m = blockIdx.x;
  int tid = threadIdx.x, lane = tid & 63, wid = tid >> 6;
  __shared__ float sb[4];
  float4 v = ((const float4*)(x + (long)m * 1024))[tid];
  float s = v.x + v.y + v.z + v.w;
  for (int off = 32; off; off >>= 1) s += __shfl_down(s, off);
  if (lane == 0) sb[wid] = s;
  __syncthreads();
  float mean = (sb[0] + sb[1] + sb[2] + sb[3]) * (1.f / 1024.f);
  __syncthreads();
  float dx = v.x - mean, dy = v.y - mean, dz = v.z - mean, dw = v.w - mean;
  float ss = dx * dx + dy * dy + dz * dz + dw * dw;
  for (int off = 32; off; off >>= 1) ss += __shfl_down(ss, off);
  if (lane == 0) sb[wid] = ss;
  __syncthreads();
  float rstd = rsqrtf((sb[0] + sb[1] + sb[2] + sb[3]) * (1.f / 1024.f) + EPS);
  __syncthreads();
  float4 wv = ((const float4*)w)[tid];
  float4 bv = ((const float4*)b)[tid];
  float4 o;
  o.x = dx * rstd * wv.x + bv.x;
  o.y = dy * rstd * wv.y + bv.y;
  o.z = dz * rstd * wv.z + bv.z;
  o.w = dw * rstd * wv.w + bv.w;
  ((float4*)(xn + (long)m * 1024))[tid] = o;
  float mx = fmaxf(fmaxf(fabsf(o.x), fabsf(o.y)), fmaxf(fabsf(o.z), fabsf(o.w)));
  for (int off = 32; off; off >>= 1) mx = fmaxf(mx, __shfl_down(mx, off));
  if (lane == 0) sb[wid] = mx;
  __syncthreads();
  if (tid == 0) rowmax[m] = fmaxf(fmaxf(sb[0], sb[1]), fmaxf(sb[2], sb[3]));
}

// ---------------- quantA: per-dest-row combined scale + gather-quantize ----------------
__global__ __launch_bounds__(256) void quantA_kernel(const float* __restrict__ xn,
                                                     const int* __restrict__ is0,
                                                     const int* __restrict__ is1,
                                                     const int* __restrict__ iv,
                                                     const float* __restrict__ rowmax,
                                                     const float* __restrict__ sums,
                                                     signed char* __restrict__ Aq,
                                                     float* __restrict__ s1) {
  int m = blockIdx.x;
  int b = m >> 8, l = m & 255;
  const float* rm = rowmax + b * 256;
  int src[15];
  src[0] = l;
#pragma unroll
  for (int j = 0; j < 3; ++j) { src[1 + j] = is0[l * 3 + j]; src[4 + j] = is1[l * 3 + j]; }
#pragma unroll
  for (int j = 0; j < 8; ++j) src[7 + j] = iv[l * 8 + j];
  float c = EPS;
#pragma unroll
  for (int sl = 0; sl < 15; ++sl) c = fmaxf(c, rm[src[sl]]);
  float xs = 127.f / c;
  if (threadIdx.x == 0) s1[m] = (sums[0] * (1.f / 15728640.f) + EPS) * c * (1.f / 127.f);
#pragma unroll
  for (int sl = 0; sl < 15; ++sl) {
    float4 v = ((const float4*)(xn + ((long)(b << 8) + src[sl]) * 1024))[threadIdx.x];
    char4 cc;
    cc.x = q8(v.x, xs); cc.y = q8(v.y, xs); cc.z = q8(v.z, xs); cc.w = q8(v.w, xs);
    *(char4*)&Aq[(long)m * 15360 + sl * 1024 + threadIdx.x * 4] = cc;
  }
}

// ---------------- fused: xag = x + s1*(acc0+acc1); LN2; quantize to int8 ----------------
__global__ __launch_bounds__(256) void ln_quant_acc_kernel(const int* __restrict__ accA,
                                                           const int* accB,
                                                           const float* __restrict__ x,
                                                           const float* __restrict__ s1,
                                                           const float* __restrict__ w,
                                                           const float* __restrict__ bb,
                                                           float* xag,
                                                           signed char* __restrict__ q,
                                                           float* __restrict__ srow,
                                                           const float* __restrict__ sum_ptr,
                                                           float inv_n) {
  int m = blockIdx.x;
  int tid = threadIdx.x, lane = tid & 63, wid = tid >> 6;
  __shared__ float sb[4];
  float sm = s1[m];
  int4 a0 = ((const int4*)(accA + (long)m * 1024))[tid];
  int4 a1 = ((const int4*)(accB + (long)m * 1024))[tid];
  float4 xv = ((const float4*)(x + (long)m * 1024))[tid];
  float4 v;
  v.x = xv.x + sm * (float)(a0.x + a1.x);
  v.y = xv.y + sm * (float)(a0.y + a1.y);
  v.z = xv.z + sm * (float)(a0.z + a1.z);
  v.w = xv.w + sm * (float)(a0.w + a1.w);
  ((float4*)(xag + (long)m * 1024))[tid] = v;
  float s = v.x + v.y + v.z + v.w;
  for (int off = 32; off; off >>= 1) s += __shfl_down(s, off);
  if (lane == 0) sb[wid] = s;
  __syncthreads();
  float mean = (sb[0] + sb[1] + sb[2] + sb[3]) * (1.f / 1024.f);
  __syncthreads();
  float dx = v.x - mean, dy = v.y - mean, dz = v.z - mean, dw = v.w - mean;
  float ss = dx * dx + dy * dy + dz * dz + dw * dw;
  for (int off = 32; off; off >>= 1) ss += __shfl_down(ss, off);
  if (lane == 0) sb[wid] = ss;
  __syncthreads();
  float rstd = rsqrtf((sb[0] + sb[1] + sb[2] + sb[3]) * (1.f / 1024.f) + EPS);
  __syncthreads();
  float4 wv = ((const float4*)w)[tid];
  float4 bv = ((const float4*)bb)[tid];
  float nx = dx * rstd * wv.x + bv.x;
  float ny = dy * rstd * wv.y + bv.y;
  float nz = dz * rstd * wv.z + bv.z;
  float nw = dw * rstd * wv.w + bv.w;
  float mx = fmaxf(fmaxf(fabsf(nx), fabsf(ny)), fmaxf(fabsf(nz), fabsf(nw)));
  for (int off = 32; off; off >>= 1) mx = fmaxf(mx, __shfl_down(mx, off));
  if (lane == 0) sb[wid] = mx;
  __syncthreads();
  float rmax = fmaxf(fmaxf(fmaxf(sb[0], sb[1]), fmaxf(sb[2], sb[3])), EPS);
  float xs = 127.f / rmax;
  char4 c;
  c.x = q8(nx, xs); c.y = q8(ny, xs); c.z = q8(nz, xs); c.w = q8(nw, xs);
  *(char4*)&q[(long)m * 1024 + tid * 4] = c;
  if (tid == 0) srow[m] = (sum_ptr[0] * inv_n + EPS) * rmax * (1.f / 127.f);
}

// ---------------- row quantize [8192,4096] bf16 -> int8 ----------------
__global__ __launch_bounds__(256) void rowquant4k_kernel(const unsigned short* __restrict__ g,
                                                         signed char* __restrict__ q,
                                                         float* __restrict__ srow,
                                                         const float* __restrict__ sum_ptr,
                                                         float inv_n) {
  int m = blockIdx.x;
  int tid = threadIdx.x, lane = tid & 63, wid = tid >> 6;
  __shared__ float sb[4];
  const uint4* gr = (const uint4*)(g + (long)m * 4096);  // 16B = 8 bf16
  float f[16];
  float mx = 0.f;
#pragma unroll
  for (int i = 0; i < 2; ++i) {
    uint4 u = gr[tid + i * 256];
    unsigned uu[4] = {u.x, u.y, u.z, u.w};
#pragma unroll
    for (int j = 0; j < 4; ++j) {
      float lo = bf2f((unsigned short)(uu[j] & 0xFFFF));
      float hi = bf2f((unsigned short)(uu[j] >> 16));
      f[i * 8 + j * 2] = lo;
      f[i * 8 + j * 2 + 1] = hi;
      mx = fmaxf(mx, fmaxf(fabsf(lo), fabsf(hi)));
    }
  }
  for (int off = 32; off; off >>= 1) mx = fmaxf(mx, __shfl_down(mx, off));
  if (lane == 0) sb[wid] = mx;
  __syncthreads();
  float rmax = fmaxf(fmaxf(fmaxf(sb[0], sb[1]), fmaxf(sb[2], sb[3])), EPS);
  float xs = 127.f / rmax;
#pragma unroll
  for (int i = 0; i < 2; ++i) {
    char4 c0, c1;
    c0.x = q8(f[i * 8 + 0], xs); c0.y = q8(f[i * 8 + 1], xs);
    c0.z = q8(f[i * 8 + 2], xs); c0.w = q8(f[i * 8 + 3], xs);
    c1.x = q8(f[i * 8 + 4], xs); c1.y = q8(f[i * 8 + 5], xs);
    c1.z = q8(f[i * 8 + 6], xs); c1.w = q8(f[i * 8 + 7], xs);
    long base = (long)m * 4096 + (tid + i * 256) * 8;
    *(char4*)&q[base] = c0;
    *(char4*)&q[base + 4] = c1;
  }
  if (tid == 0) srow[m] = (sum_ptr[0] * inv_n + EPS) * rmax * (1.f / 127.f);
}

// ---------------- final residual: out = xag + s3*(acc0+acc1) ----------------
__global__ __launch_bounds__(256) void reduce3_kernel(const int* __restrict__ accA,
                                                      const int* __restrict__ accB,
                                                      const float* __restrict__ xag,
                                                      const float* __restrict__ s3,
                                                      float* __restrict__ out) {
  int m = blockIdx.x;
  float sm = s3[m];
  int4 a0 = ((const int4*)(accA + (long)m * 1024))[threadIdx.x];
  int4 a1 = ((const int4*)(accB + (long)m * 1024))[threadIdx.x];
  float4 xv = ((const float4*)(xag + (long)m * 1024))[threadIdx.x];
  float4 o;
  o.x = xv.x + sm * (float)(a0.x + a1.x);
  o.y = xv.y + sm * (float)(a0.y + a1.y);
  o.z = xv.z + sm * (float)(a0.z + a1.z);
  o.w = xv.w + sm * (float)(a0.w + a1.w);
  ((float4*)(out + (long)m * 1024))[threadIdx.x] = o;
}

// ============================================================================
// int8 GEMM, 256x256 tile, BK=128, 8 waves (2Mx4N), 16x16x64 MFMA.
// T2: XOR-swizzled LDS via pre-swizzled global source (identical layout math to
//     the verified 128^2 kernel -> inherits fragment correctness, 0 conflicts).
// T3+T4: 2-deep double-buffer; stage tile t+2 into the buffer tile t just
//     freed, then counted `s_waitcnt vmcnt(8)` (== the 8 loads just issued, so
//     it waits only for tile t+1, issued one full tile-compute earlier) + raw
//     s_barrier. vmcnt never drains to 0 in the steady-state loop.
// T5: per-quadrant phases {12 ds_read_b128; s_barrier; setprio(1); 16 MFMA;
//     setprio(0); s_barrier} -- role-split so setprio has waves to arbitrate.
// T1: bijective XCD swizzle (grid%8==0 for all 3 GEMMs) so the blocks sharing
//     one 256-col B panel (<=2 MB, L2-fits) land on the same XCD.
// Correctness of the pipeline (audited):
//  - read(tile t) after write(tile t): issuer did vmcnt(8) at end of t-1
//    (retiring all tile-t glds) before barrier; reader passes same barrier.
//  - write(tile t+2, buf p) after read(tile t, buf p): glds issued after the
//    phase-4 trailing s_barrier; each wave's reads completed before its MFMAs
//    (compiler lgkmcnt) which precede that barrier.
//  - ds_reads alias the global_load_lds intrinsics (same LDS buffers), so the
//    compiler cannot reorder them across the staging/waitcnt block.
// mode 1: outh[m,n] = bf16(gelu(scale[m]*acc))
// mode 2: (z ? iacc1 : iacc0)[m*N+n] = acc
// ============================================================================
__device__ __forceinline__ void stage8(const signed char* __restrict__ Abase,
                                       const signed char* __restrict__ Bbase,
                                       long K, long k0,
                                       signed char* AsD, signed char* BsD, int tid) {
  const int w = tid >> 6, lane = tid & 63;
#pragma unroll
  for (int i = 0; i < 4; ++i) {
    int cb = w * 64 + i * 512;          // wave-uniform 16B-chunk base (2048 chunks total)
    int c = cb + lane;
    long row = c >> 3;                  // 0..255
    int blk = (c & 7) ^ ((c >> 3) & 7); // pre-swizzled source column block
    long gcol = k0 + ((long)blk << 4);
    glds16(Abase + row * K + gcol, AsD + cb * 16);
    glds16(Bbase + row * K + gcol, BsD + cb * 16);
  }
}

__global__ __launch_bounds__(512, 2) void gemm_i8_8w(const signed char* __restrict__ A,
                                                     const signed char* __restrict__ Bw,
                                                     __hip_bfloat16* __restrict__ outh,
                                                     int* __restrict__ iacc0,
                                                     int* __restrict__ iacc1,
                                                     const float* __restrict__ scale,
                                                     int N, long K, int nt, int mode,
                                                     int nM, int nN) {
  __shared__ __align__(16) signed char As[2 * 32768];
  __shared__ __align__(16) signed char Bs[2 * 32768];
  const int tid = threadIdx.x;
  const int lane = tid & 63;
  const int wave = tid >> 6;
  const int wm = wave >> 2, wn = wave & 3;      // 2 x 4 wave grid, 128x64 C per wave
  const int r15 = lane & 15, quad = lane >> 4, sw = lane & 7;

  // T1: bijective XCD swizzle (gridDim.x % 8 == 0 for all call sites)
  const int total = (int)gridDim.x;
  const int b = (int)blockIdx.x;
  const int g = (b & 7) * (total >> 3) + (b >> 3);
  const int mt = g % nM;
  const int rest = g / nM;
  const int ntl = rest % nN;
  const int z = rest / nN;
  const long m0 = (long)mt * 256, n0 = (long)ntl * 256;
  const signed char* Abase = A + m0 * K;
  const signed char* Bbase = Bw + n0 * K;
  const long k0base = (long)z * nt * 128;

  v4i acc[8][4] = {};

  // prologue: tiles 0,1 -> bufs 0,1; wait tile 0 (own 8 oldest loads) + barrier
  stage8(Abase, Bbase, K, k0base, As, Bs, tid);
  stage8(Abase, Bbase, K, k0base + 128, As + 32768, Bs + 32768, tid);
  asm volatile("s_waitcnt vmcnt(8)" ::: "memory");
  __builtin_amdgcn_s_barrier();

  for (int t = 0; t < nt; ++t) {
    const signed char* Ap = As + (t & 1) * 32768;
    const signed char* Bp = Bs + (t & 1) * 32768;
#pragma unroll
    for (int qm = 0; qm < 2; ++qm) {
#pragma unroll
      for (int qn = 0; qn < 2; ++qn) {
        v4i af[4][2], bfr[2][2];
#pragma unroll
        for (int m2 = 0; m2 < 4; ++m2) {
          const signed char* rp = Ap + (wm * 128 + (qm * 4 + m2) * 16 + r15) * 128;
          af[m2][0] = *(const v4i*)(rp + ((quad ^ sw) << 4));
          af[m2][1] = *(const v4i*)(rp + (((quad + 4) ^ sw) << 4));
        }
#pragma unroll
        for (int n2 = 0; n2 < 2; ++n2) {
          const signed char* rp = Bp + (wn * 64 + (qn * 2 + n2) * 16 + r15) * 128;
          bfr[n2][0] = *(const v4i*)(rp + ((quad ^ sw) << 4));
          bfr[n2][1] = *(const v4i*)(rp + (((quad + 4) ^ sw) << 4));
        }
        __builtin_amdgcn_s_barrier();
        __builtin_amdgcn_s_setprio(1);
#pragma unroll
        for (int m2 = 0; m2 < 4; ++m2) {
#pragma unroll
          for (int n2 = 0; n2 < 2; ++n2) {
            acc[qm * 4 + m2][qn * 2 + n2] = __builtin_amdgcn_mfma_i32_16x16x64_i8(
                af[m2][0], bfr[n2][0], acc[qm * 4 + m2][qn * 2 + n2], 0, 0, 0);
            acc[qm * 4 + m2][qn * 2 + n2] = __builtin_amdgcn_mfma_i32_16x16x64_i8(
                af[m2][1], bfr[n2][1], acc[qm * 4 + m2][qn * 2 + n2], 0, 0, 0);
          }
        }
        __builtin_amdgcn_s_setprio(0);
        __builtin_amdgcn_s_barrier();
      }
    }
    // staging block: buf (t&1) is now free for all waves (trailing barrier above)
    if (t + 2 < nt) {
      long k0 = k0base + (long)(t + 2) * 128;
      stage8(Abase, Bbase, K, k0, As + (t & 1) * 32768, Bs + (t & 1) * 32768, tid);
      asm volatile("s_waitcnt vmcnt(8)" ::: "memory");  // tile t+1 resident (own loads)
      __builtin_amdgcn_s_barrier();                     // ... for ALL waves
    } else if (t + 1 < nt) {
      asm volatile("s_waitcnt vmcnt(0)" ::: "memory");  // tail: drain tile t+1
      __builtin_amdgcn_s_barrier();
    }
    __builtin_amdgcn_sched_barrier(0);
  }

  // epilogue: C layout col=lane&15, row=quad*4+reg (verified in prior kernel)
  if (mode == 2) {
    int* iacc = z ? iacc1 : iacc0;
#pragma unroll
    for (int mi = 0; mi < 8; ++mi) {
#pragma unroll
      for (int r = 0; r < 4; ++r) {
        long m = m0 + wm * 128 + mi * 16 + quad * 4 + r;
        int* arow = iacc + m * N;
#pragma unroll
        for (int ni = 0; ni < 4; ++ni)
          arow[n0 + wn * 64 + ni * 16 + r15] = acc[mi][ni][r];
      }
    }
  } else {
#pragma unroll
    for (int mi = 0; mi < 8; ++mi) {
#pragma unroll
      for (int r = 0; r < 4; ++r) {
        long m = m0 + wm * 128 + mi * 16 + quad * 4 + r;
        float sm = scale[m];
        __hip_bfloat16* orow = outh + m * N;
#pragma unroll
        for (int ni = 0; ni < 4; ++ni) {
          float v = sm * (float)acc[mi][ni][r];
          orow[n0 + wn * 64 + ni * 16 + r15] =
              __float2bfloat16(0.5f * v * (1.f + erff(v * 0.70710678118654752f)));
        }
      }
    }
  }
}

extern "C" void kernel_launch(void* const* d_in, const int* in_sizes, int n_in,
                              void* d_out, int out_size, void* d_ws, size_t ws_size,
                              hipStream_t stream) {
  const float* x    = (const float*)d_in[0];
  const float* ln1w = (const float*)d_in[1];
  const float* ln1b = (const float*)d_in[2];
  const float* ln2w = (const float*)d_in[3];
  const float* ln2b = (const float*)d_in[4];
  const float* Wg   = (const float*)d_in[5];
  const float* W1   = (const float*)d_in[6];
  const float* W2   = (const float*)d_in[7];
  const int* is0    = (const int*)d_in[8];
  const int* is1    = (const int*)d_in[9];
  const int* iv     = (const int*)d_in[10];
  float* out = (float*)d_out;

  // workspace layout, peak ~234 MB (unchanged from verified r3 layout):
  char* ws = (char*)d_ws;
  float* sums = (float*)ws;                                   // 3 floats (+pad)
  signed char* t_g = (signed char*)(ws + 256);                // 15,728,640
  signed char* t_1 = t_g + 15728640;                          //  4,194,304
  signed char* t_2 = t_1 + 4194304;                           //  4,194,304
  float* rowmax1 = (float*)(t_2 + 4194304);                   // 32 KB
  float* s1  = rowmax1 + 8192;
  float* s2  = s1 + 8192;
  float* s3  = s2 + 8192;
  float* xag = s3 + 8192;
  int* acc1b = (int*)xag;
  signed char* hq = (signed char*)(xag + 8388608);            //  8.39 MB
  float* xn = (float*)(hq + 8388608);
  int* acc1a = (int*)xn;
  signed char* q3 = (signed char*)xn;
  signed char* Aq = (signed char*)(xn + 8388608);
  unsigned short* gg = (unsigned short*)Aq;
  int* acc3a = (int*)Aq;
  int* acc3b = acc3a + 8192l * 1024;

  hipMemsetAsync(sums, 0, 64, stream);
  absum3_kernel<<<1024, 256, 0, stream>>>(Wg, W1, W2, sums);
  ternarize3_kernel<<<2048, 256, 0, stream>>>(Wg, W1, W2, t_g, t_1, t_2, sums);
  ln_rowmax_kernel<<<8192, 256, 0, stream>>>(x, ln1w, ln1b, xn, rowmax1);
  quantA_kernel<<<8192, 256, 0, stream>>>(xn, is0, is1, iv, rowmax1, sums, Aq, s1);
  // GEMM1: M=8192 N=1024 K=15360, split-K=2 -> 32*4*2 = 256 blocks (1/CU)
  gemm_i8_8w<<<256, 512, 0, stream>>>(Aq, t_g, nullptr, acc1a, acc1b, nullptr,
                                      1024, 15360L, 60, 2, 32, 4);
  ln_quant_acc_kernel<<<8192, 256, 0, stream>>>(acc1a, acc1b, x, s1, ln2w, ln2b, xag, hq, s2,
                                                &sums[1], 1.f / 4194304.f);
  // GEMM2: M=8192 N=4096 K=1024, gelu -> bf16, 32*16 = 512 blocks
  gemm_i8_8w<<<512, 512, 0, stream>>>(hq, t_1, (__hip_bfloat16*)gg, nullptr, nullptr,
                                      s2, 4096, 1024L, 8, 1, 32, 16);
  rowquant4k_kernel<<<8192, 256, 0, stream>>>(gg, q3, s3, &sums[2], 1.f / 4194304.f);
  // GEMM3: M=8192 N=1024 K=4096, split-K=2 -> 256 blocks
  gemm_i8_8w<<<256, 512, 0, stream>>>(q3, t_2, nullptr, acc3a, acc3b, nullptr,
                                      1024, 4096L, 16, 2, 32, 4);
  reduce3_kernel<<<8192, 256, 0, stream>>>(acc3a, acc3b, xag, s3, out);
}

// Round 2
// 533.964 us; speedup vs baseline: 1.2363x; 1.2363x over previous
//
#include <hip/hip_runtime.h>
#include <hip/hip_bf16.h>
#include <math.h>
#include <stdint.h>

#define EPS 1e-5f

typedef int v4i __attribute__((ext_vector_type(4)));

__device__ __forceinline__ void glds16(const void* g, void* l) {
  __builtin_amdgcn_global_load_lds(
      (const __attribute__((address_space(1))) void*)g,
      (__attribute__((address_space(3))) void*)l, 16, 0, 0);
}

__device__ __forceinline__ signed char q8(float f, float xs) {
  float r = rintf(f * xs);
  r = fminf(fmaxf(r, -128.f), 127.f);
  return (signed char)(int)r;
}

__device__ __forceinline__ float bf2f(unsigned short h) {
  return __builtin_bit_cast(float, (unsigned)h << 16);
}

// ---------------- merged weight abs-sum (3 tensors, 1 launch) ----------------
__global__ __launch_bounds__(256) void absum3_kernel(const float* __restrict__ Wg,
                                                     const float* __restrict__ W1,
                                                     const float* __restrict__ W2,
                                                     float* __restrict__ out) {
  int blk = blockIdx.x;
  const float* w; long n4; float* o; long lb; long nb;
  if (blk < 512)      { w = Wg; n4 = 3932160; o = &out[0]; lb = blk;       nb = 512; }
  else if (blk < 768) { w = W1; n4 = 1048576; o = &out[1]; lb = blk - 512; nb = 256; }
  else                { w = W2; n4 = 1048576; o = &out[2]; lb = blk - 768; nb = 256; }
  const float4* w4 = (const float4*)w;
  float s = 0.f;
  for (long i = lb * 256 + threadIdx.x; i < n4; i += nb * 256) {
    float4 v = w4[i];
    s += fabsf(v.x) + fabsf(v.y) + fabsf(v.z) + fabsf(v.w);
  }
  for (int off = 32; off; off >>= 1) s += __shfl_down(s, off);
  __shared__ float sb[4];
  int lane = threadIdx.x & 63, wid = threadIdx.x >> 6;
  if (lane == 0) sb[wid] = s;
  __syncthreads();
  if (threadIdx.x == 0) atomicAdd(o, sb[0] + sb[1] + sb[2] + sb[3]);
}

// ---------------- merged ternarize (3 tensors, 1 launch) ----------------
__global__ __launch_bounds__(256) void ternarize3_kernel(const float* __restrict__ Wg,
                                                         const float* __restrict__ W1,
                                                         const float* __restrict__ W2,
                                                         signed char* __restrict__ tg,
                                                         signed char* __restrict__ t1,
                                                         signed char* __restrict__ t2,
                                                         const float* __restrict__ sums) {
  int blk = blockIdx.x;
  const float* w; signed char* t; long n4; float ws; long lb; long nb;
  if (blk < 1024) {
    w = Wg; t = tg; n4 = 3932160; ws = sums[0] * (1.f / 15728640.f) + EPS; lb = blk; nb = 1024;
  } else if (blk < 1536) {
    w = W1; t = t1; n4 = 1048576; ws = sums[1] * (1.f / 4194304.f) + EPS; lb = blk - 1024; nb = 512;
  } else {
    w = W2; t = t2; n4 = 1048576; ws = sums[2] * (1.f / 4194304.f) + EPS; lb = blk - 1536; nb = 512;
  }
  const float4* w4 = (const float4*)w;
  char4* t4 = (char4*)t;
  for (long i = lb * 256 + threadIdx.x; i < n4; i += nb * 256) {
    float4 v = w4[i];
    char4 c;
    c.x = (signed char)(int)fminf(fmaxf(rintf(v.x / ws), -1.f), 1.f);
    c.y = (signed char)(int)fminf(fmaxf(rintf(v.y / ws), -1.f), 1.f);
    c.z = (signed char)(int)fminf(fmaxf(rintf(v.z / ws), -1.f), 1.f);
    c.w = (signed char)(int)fminf(fmaxf(rintf(v.w / ws), -1.f), 1.f);
    t4[i] = c;
  }
}

// ---------------- LN1: write xn fp32 + per-row absmax ----------------
__global__ __launch_bounds__(256) void ln_rowmax_kernel(const float* __restrict__ x,
                                                        const float* __restrict__ w,
                                                        const float* __restrict__ b,
                                                        float* __restrict__ xn,
                                                        float* __restrict__ rowmax) {
  int m = blockIdx.x;
  int tid = threadIdx.x, lane = tid & 63, wid = tid >> 6;
  __shared__ float sb[4];
  float4 v = ((const float4*)(x + (long)m * 1024))[tid];
  float s = v.x + v.y + v.z + v.w;
  for (int off = 32; off; off >>= 1) s += __shfl_down(s, off);
  if (lane == 0) sb[wid] = s;
  __syncthreads();
  float mean = (sb[0] + sb[1] + sb[2] + sb[3]) * (1.f / 1024.f);
  __syncthreads();
  float dx = v.x - mean, dy = v.y - mean, dz = v.z - mean, dw = v.w - mean;
  float ss = dx * dx + dy * dy + dz * dz + dw * dw;
  for (int off = 32; off; off >>= 1) ss += __shfl_down(ss, off);
  if (lane == 0) sb[wid] = ss;
  __syncthreads();
  float rstd = rsqrtf((sb[0] + sb[1] + sb[2] + sb[3]) * (1.f / 1024.f) + EPS);
  __syncthreads();
  float4 wv = ((const float4*)w)[tid];
  float4 bv = ((const float4*)b)[tid];
  float4 o;
  o.x = dx * rstd * wv.x + bv.x;
  o.y = dy * rstd * wv.y + bv.y;
  o.z = dz * rstd * wv.z + bv.z;
  o.w = dw * rstd * wv.w + bv.w;
  ((float4*)(xn + (long)m * 1024))[tid] = o;
  float mx = fmaxf(fmaxf(fabsf(o.x), fabsf(o.y)), fmaxf(fabsf(o.z), fabsf(o.w)));
  for (int off = 32; off; off >>= 1) mx = fmaxf(mx, __shfl_down(mx, off));
  if (lane == 0) sb[wid] = mx;
  __syncthreads();
  if (tid == 0) rowmax[m] = fmaxf(fmaxf(sb[0], sb[1]), fmaxf(sb[2], sb[3]));
}

// ---------------- quantA: per-dest-row combined scale + gather-quantize ----------------
__global__ __launch_bounds__(256) void quantA_kernel(const float* __restrict__ xn,
                                                     const int* __restrict__ is0,
                                                     const int* __restrict__ is1,
                                                     const int* __restrict__ iv,
                                                     const float* __restrict__ rowmax,
                                                     const float* __restrict__ sums,
                                                     signed char* __restrict__ Aq,
                                                     float* __restrict__ s1) {
  int m = blockIdx.x;
  int b = m >> 8, l = m & 255;
  const float* rm = rowmax + b * 256;
  int src[15];
  src[0] = l;
#pragma unroll
  for (int j = 0; j < 3; ++j) { src[1 + j] = is0[l * 3 + j]; src[4 + j] = is1[l * 3 + j]; }
#pragma unroll
  for (int j = 0; j < 8; ++j) src[7 + j] = iv[l * 8 + j];
  float c = EPS;
#pragma unroll
  for (int sl = 0; sl < 15; ++sl) c = fmaxf(c, rm[src[sl]]);
  float xs = 127.f / c;
  if (threadIdx.x == 0) s1[m] = (sums[0] * (1.f / 15728640.f) + EPS) * c * (1.f / 127.f);
#pragma unroll
  for (int sl = 0; sl < 15; ++sl) {
    float4 v = ((const float4*)(xn + ((long)(b << 8) + src[sl]) * 1024))[threadIdx.x];
    char4 cc;
    cc.x = q8(v.x, xs); cc.y = q8(v.y, xs); cc.z = q8(v.z, xs); cc.w = q8(v.w, xs);
    *(char4*)&Aq[(long)m * 15360 + sl * 1024 + threadIdx.x * 4] = cc;
  }
}

// ---------------- fused: xag = x + s1*(acc0+acc1); LN2; quantize to int8 ----------------
__global__ __launch_bounds__(256) void ln_quant_acc_kernel(const int* __restrict__ accA,
                                                           const int* accB,
                                                           const float* __restrict__ x,
                                                           const float* __restrict__ s1,
                                                           const float* __restrict__ w,
                                                           const float* __restrict__ bb,
                                                           float* xag,
                                                           signed char* __restrict__ q,
                                                           float* __restrict__ srow,
                                                           const float* __restrict__ sum_ptr,
                                                           float inv_n) {
  int m = blockIdx.x;
  int tid = threadIdx.x, lane = tid & 63, wid = tid >> 6;
  __shared__ float sb[4];
  float sm = s1[m];
  int4 a0 = ((const int4*)(accA + (long)m * 1024))[tid];
  int4 a1 = ((const int4*)(accB + (long)m * 1024))[tid];
  float4 xv = ((const float4*)(x + (long)m * 1024))[tid];
  float4 v;
  v.x = xv.x + sm * (float)(a0.x + a1.x);
  v.y = xv.y + sm * (float)(a0.y + a1.y);
  v.z = xv.z + sm * (float)(a0.z + a1.z);
  v.w = xv.w + sm * (float)(a0.w + a1.w);
  ((float4*)(xag + (long)m * 1024))[tid] = v;
  float s = v.x + v.y + v.z + v.w;
  for (int off = 32; off; off >>= 1) s += __shfl_down(s, off);
  if (lane == 0) sb[wid] = s;
  __syncthreads();
  float mean = (sb[0] + sb[1] + sb[2] + sb[3]) * (1.f / 1024.f);
  __syncthreads();
  float dx = v.x - mean, dy = v.y - mean, dz = v.z - mean, dw = v.w - mean;
  float ss = dx * dx + dy * dy + dz * dz + dw * dw;
  for (int off = 32; off; off >>= 1) ss += __shfl_down(ss, off);
  if (lane == 0) sb[wid] = ss;
  __syncthreads();
  float rstd = rsqrtf((sb[0] + sb[1] + sb[2] + sb[3]) * (1.f / 1024.f) + EPS);
  __syncthreads();
  float4 wv = ((const float4*)w)[tid];
  float4 bv = ((const float4*)bb)[tid];
  float nx = dx * rstd * wv.x + bv.x;
  float ny = dy * rstd * wv.y + bv.y;
  float nz = dz * rstd * wv.z + bv.z;
  float nw = dw * rstd * wv.w + bv.w;
  float mx = fmaxf(fmaxf(fabsf(nx), fabsf(ny)), fmaxf(fabsf(nz), fabsf(nw)));
  for (int off = 32; off; off >>= 1) mx = fmaxf(mx, __shfl_down(mx, off));
  if (lane == 0) sb[wid] = mx;
  __syncthreads();
  float rmax = fmaxf(fmaxf(fmaxf(sb[0], sb[1]), fmaxf(sb[2], sb[3])), EPS);
  float xs = 127.f / rmax;
  char4 c;
  c.x = q8(nx, xs); c.y = q8(ny, xs); c.z = q8(nz, xs); c.w = q8(nw, xs);
  *(char4*)&q[(long)m * 1024 + tid * 4] = c;
  if (tid == 0) srow[m] = (sum_ptr[0] * inv_n + EPS) * rmax * (1.f / 127.f);
}

// ---------------- row quantize [8192,4096] bf16 -> int8 ----------------
__global__ __launch_bounds__(256) void rowquant4k_kernel(const unsigned short* __restrict__ g,
                                                         signed char* __restrict__ q,
                                                         float* __restrict__ srow,
                                                         const float* __restrict__ sum_ptr,
                                                         float inv_n) {
  int m = blockIdx.x;
  int tid = threadIdx.x, lane = tid & 63, wid = tid >> 6;
  __shared__ float sb[4];
  const uint4* gr = (const uint4*)(g + (long)m * 4096);  // 16B = 8 bf16
  float f[16];
  float mx = 0.f;
#pragma unroll
  for (int i = 0; i < 2; ++i) {
    uint4 u = gr[tid + i * 256];
    unsigned uu[4] = {u.x, u.y, u.z, u.w};
#pragma unroll
    for (int j = 0; j < 4; ++j) {
      float lo = bf2f((unsigned short)(uu[j] & 0xFFFF));
      float hi = bf2f((unsigned short)(uu[j] >> 16));
      f[i * 8 + j * 2] = lo;
      f[i * 8 + j * 2 + 1] = hi;
      mx = fmaxf(mx, fmaxf(fabsf(lo), fabsf(hi)));
    }
  }
  for (int off = 32; off; off >>= 1) mx = fmaxf(mx, __shfl_down(mx, off));
  if (lane == 0) sb[wid] = mx;
  __syncthreads();
  float rmax = fmaxf(fmaxf(fmaxf(sb[0], sb[1]), fmaxf(sb[2], sb[3])), EPS);
  float xs = 127.f / rmax;
#pragma unroll
  for (int i = 0; i < 2; ++i) {
    char4 c0, c1;
    c0.x = q8(f[i * 8 + 0], xs); c0.y = q8(f[i * 8 + 1], xs);
    c0.z = q8(f[i * 8 + 2], xs); c0.w = q8(f[i * 8 + 3], xs);
    c1.x = q8(f[i * 8 + 4], xs); c1.y = q8(f[i * 8 + 5], xs);
    c1.z = q8(f[i * 8 + 6], xs); c1.w = q8(f[i * 8 + 7], xs);
    long base = (long)m * 4096 + (tid + i * 256) * 8;
    *(char4*)&q[base] = c0;
    *(char4*)&q[base + 4] = c1;
  }
  if (tid == 0) srow[m] = (sum_ptr[0] * inv_n + EPS) * rmax * (1.f / 127.f);
}

// ---------------- final residual: out = xag + s3*(acc0+acc1) ----------------
__global__ __launch_bounds__(256) void reduce3_kernel(const int* __restrict__ accA,
                                                      const int* __restrict__ accB,
                                                      const float* __restrict__ xag,
                                                      const float* __restrict__ s3,
                                                      float* __restrict__ out) {
  int m = blockIdx.x;
  float sm = s3[m];
  int4 a0 = ((const int4*)(accA + (long)m * 1024))[threadIdx.x];
  int4 a1 = ((const int4*)(accB + (long)m * 1024))[threadIdx.x];
  float4 xv = ((const float4*)(xag + (long)m * 1024))[threadIdx.x];
  float4 o;
  o.x = xv.x + sm * (float)(a0.x + a1.x);
  o.y = xv.y + sm * (float)(a0.y + a1.y);
  o.z = xv.z + sm * (float)(a0.z + a1.z);
  o.w = xv.w + sm * (float)(a0.w + a1.w);
  ((float4*)(out + (long)m * 1024))[threadIdx.x] = o;
}

// ============================================================================
// int8 GEMM, 256x256 tile, BK=128, 8 waves (2Mx4N), 16x16x64 MFMA.
// r2 redesign after r1 post-mortem (MfmaUtil 23%): at 1 block/CU (acc=128
// AGPR/wave forces it), LDS-read windows and MFMA windows must OVERLAP, and
// fragments must be read exactly once.
//  - Fragments held in regs: A-half a0,a1 (8 v4i each), B-halves b0,b1 (4 each)
//    = 24 v4i (96 VGPR) + 128 AGPR acc -> ~245 regs, fits 2 waves/SIMD.
//  - Quadrant order 00 -> 01 -> 10 -> 11; every ds_read issued >=1 MFMA phase
//    before its counted lgkmcnt wait (DS queue retires in order):
//      ph0: issue b1,a1(tile t);  lgkm(12) waits a0,b0 (issued t-1.ph3)
//      ph1: lgkm(8)  waits b1     (a1 floats)
//      ph2: lgkm(0)  waits a1; BARRIER(all buf-p reads done); glds t+2 -> buf p
//      ph3: vmcnt(8) waits t+1's glds (issued t-1.ph2); BARRIER; issue
//           a0',b0'(tile t+1, buf 1-p) under MFMA11.
//    4 barriers/tile (vs 9 in r1); vmcnt never drains to 0 mid-loop (T4).
//  - Per rule 18, every inline s_waitcnt is followed by sched_barrier(0);
//    read-issue blocks are pinned with sched_barrier(0) so they can't sink
//    past the MFMA cluster.
//  - XOR swizzle (T2) unchanged from the harness-verified r0/r1 layout:
//    pre-swizzled global source, linear glds dest, swizzled ds_read.
//  - No XCD swizzle: mt fastest => same-mt blocks land on same XCD
//    (mt+32k = mt mod 8), giving A-panel L2 reuse (r0's measured behavior).
// mode 1: outh[m,n] = bf16(gelu(scale[m]*acc));  mode 2: iacc store.
// ============================================================================

#define LGKM(n) do { asm volatile("s_waitcnt lgkmcnt(" #n ")" ::: "memory"); \
                     __builtin_amdgcn_sched_barrier(0); } while (0)
#define VMC(n)  do { asm volatile("s_waitcnt vmcnt(" #n ")" ::: "memory");   \
                     __builtin_amdgcn_sched_barrier(0); } while (0)
#define SBAR    __builtin_amdgcn_s_barrier()
#define SCHED0  __builtin_amdgcn_sched_barrier(0)

// one C-quadrant (QM,QN): 16 MFMA, all-static acc indexing
#define MFQ(Af, Bf, QM, QN)                                                    \
  do {                                                                         \
    __builtin_amdgcn_s_setprio(1);                                             \
    _Pragma("unroll") for (int m2 = 0; m2 < 4; ++m2) {                         \
      _Pragma("unroll") for (int n2 = 0; n2 < 2; ++n2) {                       \
        acc[(QM)*4 + m2][(QN)*2 + n2] = __builtin_amdgcn_mfma_i32_16x16x64_i8( \
            Af[m2][0], Bf[n2][0], acc[(QM)*4 + m2][(QN)*2 + n2], 0, 0, 0);     \
        acc[(QM)*4 + m2][(QN)*2 + n2] = __builtin_amdgcn_mfma_i32_16x16x64_i8( \
            Af[m2][1], Bf[n2][1], acc[(QM)*4 + m2][(QN)*2 + n2], 0, 0, 0);     \
      }                                                                        \
    }                                                                          \
    __builtin_amdgcn_s_setprio(0);                                             \
  } while (0)

// read one A-half (8 ds_read_b128) / one B-half (4 ds_read_b128)
#define RDA(arr, BO, QMOFS)                                                    \
  _Pragma("unroll") for (int m2 = 0; m2 < 4; ++m2) {                           \
    arr[m2][0] = *(const v4i*)(pA0 + (BO) + (QMOFS) + m2 * 2048);              \
    arr[m2][1] = *(const v4i*)(pA1 + (BO) + (QMOFS) + m2 * 2048);              \
  }
#define RDB(arr, BO, QNOFS)                                                    \
  _Pragma("unroll") for (int n2 = 0; n2 < 2; ++n2) {                           \
    arr[n2][0] = *(const v4i*)(pB0 + (BO) + (QNOFS) + n2 * 2048);              \
    arr[n2][1] = *(const v4i*)(pB1 + (BO) + (QNOFS) + n2 * 2048);              \
  }

__global__ __launch_bounds__(512, 2) void gemm_i8_p(const signed char* __restrict__ A,
                                                    const signed char* __restrict__ Bw,
                                                    __hip_bfloat16* __restrict__ outh,
                                                    int* __restrict__ iacc0,
                                                    int* __restrict__ iacc1,
                                                    const float* __restrict__ scale,
                                                    int N, long K, int nt, int mode,
                                                    int nM, int nN) {
  __shared__ __align__(16) signed char lds[131072];  // A: [0,64K), B: [64K,128K)
  const int tid = threadIdx.x;
  const int lane = tid & 63;
  const int wave = tid >> 6;
  const int wm = wave >> 2, wn = wave & 3;  // 2x4 wave grid, 128x64 C per wave
  const int r15 = lane & 15, quad = lane >> 4, sw = lane & 7;

  // mt fastest (no XCD swizzle: same-mt => same XCD => A-panel L2 reuse)
  const int g = (int)blockIdx.x;
  const int mt = g % nM;
  const int rest = g / nM;
  const int ntl = rest % nN;
  const int z = rest / nN;
  const long m0 = (long)mt * 256, n0 = (long)ntl * 256;
  const signed char* Ab = A + m0 * K;
  const signed char* Bb = Bw + n0 * K;
  const long k0base = (long)z * nt * 128;

  // glds per-lane 32-bit global offsets (4 chunks; identical for A and B)
  unsigned voff[4];
#pragma unroll
  for (int i = 0; i < 4; ++i) {
    int c = wave * 64 + i * 512 + lane;
    int row = c >> 3;
    int blk = (c & 7) ^ (row & 7);  // pre-swizzled source column block
    voff[i] = (unsigned)row * (unsigned)K + (unsigned)(blk << 4);
  }

  // ds_read base pointers (k-slice 0/1 have different XOR'd column offsets)
  const signed char* pA0 = lds + (wm * 128 + r15) * 128 + ((quad ^ sw) << 4);
  const signed char* pA1 = lds + (wm * 128 + r15) * 128 + (((quad + 4) ^ sw) << 4);
  const signed char* pB0 = lds + 65536 + (wn * 64 + r15) * 128 + ((quad ^ sw) << 4);
  const signed char* pB1 = lds + 65536 + (wn * 64 + r15) * 128 + (((quad + 4) ^ sw) << 4);

  v4i a0[4][2], a1[4][2], b0[2][2], b1[2][2];
  v4i acc[8][4] = {};

#define STAGE(BO, KOFF)                                                        \
  _Pragma("unroll") for (int i = 0; i < 4; ++i) {                              \
    int cb = wave * 64 + i * 512;                                              \
    glds16(Ab + (KOFF) + voff[i], (void*)(lds + (BO) + cb * 16));              \
    glds16(Bb + (KOFF) + voff[i], (void*)(lds + 65536 + (BO) + cb * 16));      \
  }

  // ---- prologue: stage tiles 0,1; wait tile 0 (own 8 oldest); read a0,b0 ----
  STAGE(0, k0base);
  STAGE(32768, k0base + 128);
  VMC(8);
  SBAR;
  RDA(a0, 0, 0);
  RDB(b0, 0, 0);
  SCHED0;

  for (int t = 0; t < nt; ++t) {
    const int bo = (t & 1) << 15;
    const int bn = bo ^ 32768;
    // ---- ph0: issue b1 then a1 (order matters for counted lgkm) ----
    RDB(b1, bo, 4096);
    RDA(a1, bo, 8192);
    SCHED0;
    SBAR;
    LGKM(12);  // queue: [a0(8),b0(4) | b1(4),a1(8)] -> waits a0,b0
    MFQ(a0, b0, 0, 0);
    SBAR;
    // ---- ph1 ----
    LGKM(8);   // waits b1 (a1 floats)
    MFQ(a0, b1, 0, 1);
    // ---- ph2 ----
    LGKM(0);   // a1 done (this wave)
    SBAR;      // ALL waves done reading buf p -> safe to overwrite
    if (t + 2 < nt) { STAGE(bo, k0base + (long)(t + 2) * 128); }
    MFQ(a1, b0, 1, 0);
    // ---- ph3 ----
    if (t + 2 < nt) { VMC(8); }  // tile t+1 resident (8 newest = t+2's glds)
    else           { VMC(0); }   // tail drain
    SBAR;                         // buf 1-p ready for all waves
    if (t + 1 < nt) {
      RDA(a0, bn, 0);  // next tile's a0 (slots dead since ph1)
      RDB(b0, bn, 0);  // next tile's b0 (slots dead since ph2)
      SCHED0;
    }
    MFQ(a1, b1, 1, 1);
  }

  // ---- epilogue: C layout col=lane&15, row=quad*4+reg (harness-verified) ----
  if (mode == 2) {
    int* iacc = z ? iacc1 : iacc0;
#pragma unroll
    for (int mi = 0; mi < 8; ++mi) {
#pragma unroll
      for (int r = 0; r < 4; ++r) {
        long m = m0 + wm * 128 + mi * 16 + quad * 4 + r;
        int* arow = iacc + m * N;
#pragma unroll
        for (int ni = 0; ni < 4; ++ni)
          arow[n0 + wn * 64 + ni * 16 + r15] = acc[mi][ni][r];
      }
    }
  } else {
#pragma unroll
    for (int mi = 0; mi < 8; ++mi) {
#pragma unroll
      for (int r = 0; r < 4; ++r) {
        long m = m0 + wm * 128 + mi * 16 + quad * 4 + r;
        float sm = scale[m];
        __hip_bfloat16* orow = outh + m * N;
#pragma unroll
        for (int ni = 0; ni < 4; ++ni) {
          float v = sm * (float)acc[mi][ni][r];
          orow[n0 + wn * 64 + ni * 16 + r15] =
              __float2bfloat16(0.5f * v * (1.f + erff(v * 0.70710678118654752f)));
        }
      }
    }
  }
}

extern "C" void kernel_launch(void* const* d_in, const int* in_sizes, int n_in,
                              void* d_out, int out_size, void* d_ws, size_t ws_size,
                              hipStream_t stream) {
  const float* x    = (const float*)d_in[0];
  const float* ln1w = (const float*)d_in[1];
  const float* ln1b = (const float*)d_in[2];
  const float* ln2w = (const float*)d_in[3];
  const float* ln2b = (const float*)d_in[4];
  const float* Wg   = (const float*)d_in[5];
  const float* W1   = (const float*)d_in[6];
  const float* W2   = (const float*)d_in[7];
  const int* is0    = (const int*)d_in[8];
  const int* is1    = (const int*)d_in[9];
  const int* iv     = (const int*)d_in[10];
  float* out = (float*)d_out;

  // workspace layout, peak ~234 MB (unchanged from verified layout):
  char* ws = (char*)d_ws;
  float* sums = (float*)ws;                                   // 3 floats (+pad)
  signed char* t_g = (signed char*)(ws + 256);                // 15,728,640
  signed char* t_1 = t_g + 15728640;                          //  4,194,304
  signed char* t_2 = t_1 + 4194304;                           //  4,194,304
  float* rowmax1 = (float*)(t_2 + 4194304);                   // 32 KB
  float* s1  = rowmax1 + 8192;
  float* s2  = s1 + 8192;
  float* s3  = s2 + 8192;
  float* xag = s3 + 8192;
  int* acc1b = (int*)xag;
  signed char* hq = (signed char*)(xag + 8388608);            //  8.39 MB
  float* xn = (float*)(hq + 8388608);
  int* acc1a = (int*)xn;
  signed char* q3 = (signed char*)xn;
  signed char* Aq = (signed char*)(xn + 8388608);
  unsigned short* gg = (unsigned short*)Aq;
  int* acc3a = (int*)Aq;
  int* acc3b = acc3a + 8192l * 1024;

  hipMemsetAsync(sums, 0, 64, stream);
  absum3_kernel<<<1024, 256, 0, stream>>>(Wg, W1, W2, sums);
  ternarize3_kernel<<<2048, 256, 0, stream>>>(Wg, W1, W2, t_g, t_1, t_2, sums);
  ln_rowmax_kernel<<<8192, 256, 0, stream>>>(x, ln1w, ln1b, xn, rowmax1);
  quantA_kernel<<<8192, 256, 0, stream>>>(xn, is0, is1, iv, rowmax1, sums, Aq, s1);
  // GEMM1: M=8192 N=1024 K=15360, split-K=2 -> 32*4*2 = 256 blocks (1/CU)
  gemm_i8_p<<<256, 512, 0, stream>>>(Aq, t_g, nullptr, acc1a, acc1b, nullptr,
                                     1024, 15360L, 60, 2, 32, 4);
  ln_quant_acc_kernel<<<8192, 256, 0, stream>>>(acc1a, acc1b, x, s1, ln2w, ln2b, xag, hq, s2,
                                                &sums[1], 1.f / 4194304.f);
  // GEMM2: M=8192 N=4096 K=1024, gelu -> bf16, 32*16 = 512 blocks
  gemm_i8_p<<<512, 512, 0, stream>>>(hq, t_1, (__hip_bfloat16*)gg, nullptr, nullptr,
                                     s2, 4096, 1024L, 8, 1, 32, 16);
  rowquant4k_kernel<<<8192, 256, 0, stream>>>(gg, q3, s3, &sums[2], 1.f / 4194304.f);
  // GEMM3: M=8192 N=1024 K=4096, split-K=2 -> 256 blocks
  gemm_i8_p<<<256, 512, 0, stream>>>(q3, t_2, nullptr, acc3a, acc3b, nullptr,
                                     1024, 4096L, 16, 2, 32, 4);
  reduce3_kernel<<<8192, 256, 0, stream>>>(acc3a, acc3b, xag, s3, out);
}